// Round 1
// baseline (265.837 us; speedup 1.0000x reference)
//
#include <hip/hip_runtime.h>

// Sizes fixed by the problem: N=64 nodes, H=64, M=32, B=16384.
#define NBATCH 16384
#define TB     128          // batch rows per block
#define PITCH  72           // LDS activation pitch in bf16 elems (144B = 9*16B -> 2-way bank alias only)

typedef short bf16x8 __attribute__((ext_vector_type(8)));
typedef float f32x4  __attribute__((ext_vector_type(4)));

__device__ __forceinline__ unsigned short f2bf(float f) {
    union { float f; unsigned int u; } v; v.f = f;
    unsigned int u = v.u;
    u = (u + 0x7FFFu + ((u >> 16) & 1u)) >> 16;   // RNE
    return (unsigned short)u;
}

__device__ __forceinline__ f32x4 mfma16(bf16x8 a, bf16x8 b, f32x4 c) {
    return __builtin_amdgcn_mfma_f32_16x16x32_bf16(a, b, c, 0, 0, 0);
}

// ws layout (ushort elems): xb[1048576] w1a[262144] w1b[131072] w2a[262144] w2b[131072] w3a64[262144] | w3x float[4096]
#define WS_XB    0
#define WS_W1A   1048576
#define WS_W1B   (WS_W1A + 262144)
#define WS_W2A   (WS_W1B + 131072)
#define WS_W2B   (WS_W2A + 262144)
#define WS_W3A   (WS_W2B + 131072)
#define WS_END   (WS_W3A + 262144)   // 2097152 ushorts; w3x floats start here

__global__ void prep_kernel(const float* __restrict__ x,
                            const float* __restrict__ W1a,
                            const float* __restrict__ W1b,
                            const float* __restrict__ W2a,
                            const float* __restrict__ W2b,
                            const float* __restrict__ W3a,
                            unsigned short* __restrict__ wsu,
                            float* __restrict__ w3x) {
    int j = blockIdx.x * 256 + threadIdx.x;
    if (j < 1048576) wsu[WS_XB + j] = f2bf(x[j]);
    if (j < 262144) {
        wsu[WS_W1A + j] = f2bf(W1a[j]);
        wsu[WS_W2A + j] = f2bf(W2a[j]);
        int i = j >> 12, h = (j >> 6) & 63, k = j & 63;
        wsu[WS_W3A + j] = f2bf(W3a[(i << 13) + (h << 7) + k]);   // first 64 cols of W3a
    }
    if (j < 131072) {
        wsu[WS_W1B + j] = f2bf(W1b[j]);
        wsu[WS_W2B + j] = f2bf(W2b[j]);
    }
    if (j < 4096) {
        int i = j >> 6, h = j & 63;
        w3x[j] = W3a[(i << 13) + (h << 7) + 64 + i];             // rank-1 column (kept fp32)
    }
}

__global__ __launch_bounds__(256, 2) void main_kernel(
    const float* __restrict__ x,
    const float* __restrict__ b3a,
    const float* __restrict__ W3b,
    const float* __restrict__ b3b,
    const unsigned short* __restrict__ wsu,
    const float* __restrict__ w3x,
    float* __restrict__ out)
{
    const unsigned short* xb  = wsu + WS_XB;
    const unsigned short* w1a = wsu + WS_W1A;
    const unsigned short* w1b = wsu + WS_W1B;
    const unsigned short* w2a = wsu + WS_W2A;
    const unsigned short* w2b = wsu + WS_W2B;
    const unsigned short* w3a = wsu + WS_W3A;

    __shared__ unsigned short Xs[TB * PITCH];   // masked x (col i zeroed), bf16
    __shared__ unsigned short Ha[TB * PITCH];   // hidden, directed branch
    __shared__ unsigned short Hb[TB * PITCH];   // hidden, bi branch
    __shared__ unsigned short R12[TB * PITCH];  // r1 | r2 concat
    __shared__ float xdiag[TB];                 // fp32 x[b,i]

    const int i    = blockIdx.x & 63;
    const int b0   = (blockIdx.x >> 6) << 7;    // *TB
    const int tid  = threadIdx.x;
    const int w    = tid >> 6;
    const int lane = tid & 63;
    const int q    = lane >> 4;
    const int c0   = lane & 15;

    // ---------------- stage masked x tile ----------------
    {
        const int ihi = i >> 2, ilo = i & 3;
        #pragma unroll
        for (int it = 0; it < 8; ++it) {
            int idx = tid + (it << 8);          // 0..2047 chunks of 4 bf16
            int r  = idx >> 4;
            int cc = idx & 15;
            union { uint2 u2; unsigned short s[4]; } v;
            v.u2 = *(const uint2*)&xb[((b0 + r) << 6) + (cc << 2)];
            if (cc == ihi) v.s[ilo] = 0;        // zero column i
            *(uint2*)&Xs[r * PITCH + (cc << 2)] = v.u2;
        }
        if (tid < TB) xdiag[tid] = x[((b0 + tid) << 6) + i];
    }
    __syncthreads();

    // ---------------- phase A: X -> Ha (W1a), X -> Hb (W2a), K=64, out=64 ----------------
    {
        const unsigned short* Wp1 = w1a + (i << 12);
        const unsigned short* Wp2 = w2a + (i << 12);
        bf16x8 A1[4][2], A2[4][2];
        #pragma unroll
        for (int t = 0; t < 4; ++t)
            #pragma unroll
            for (int s = 0; s < 2; ++s) {
                int off = (((t << 4) + c0) << 6) + (s << 5) + (q << 3);
                A1[t][s] = *(const bf16x8*)&Wp1[off];
                A2[t][s] = *(const bf16x8*)&Wp2[off];
            }
        #pragma unroll
        for (int cc = 0; cc < 2; ++cc) {
            int rb = (((w << 1) + cc) * 16 + c0) * PITCH;
            bf16x8 B0 = *(const bf16x8*)&Xs[rb + (q << 3)];
            bf16x8 B1 = *(const bf16x8*)&Xs[rb + 32 + (q << 3)];
            #pragma unroll
            for (int t = 0; t < 4; ++t) {
                f32x4 a1 = {0.f, 0.f, 0.f, 0.f};
                a1 = mfma16(A1[t][0], B0, a1);
                a1 = mfma16(A1[t][1], B1, a1);
                f32x4 a2 = {0.f, 0.f, 0.f, 0.f};
                a2 = mfma16(A2[t][0], B0, a2);
                a2 = mfma16(A2[t][1], B1, a2);
                union { uint2 u2; unsigned short s[4]; } p1, p2;
                #pragma unroll
                for (int r = 0; r < 4; ++r) {
                    p1.s[r] = f2bf(fmaxf(a1[r], 0.f));
                    p2.s[r] = f2bf(fmaxf(a2[r], 0.f));
                }
                int woff = rb + (t << 4) + (q << 2);
                *(uint2*)&Ha[woff] = p1.u2;
                *(uint2*)&Hb[woff] = p2.u2;
            }
        }
    }
    __syncthreads();

    // ---------------- phase B: Ha -> R12[:,0:32] (W1b), Hb -> R12[:,32:64] (W2b), K=64, out=32 ----------------
    {
        const unsigned short* Wp1 = w1b + (i << 11);
        const unsigned short* Wp2 = w2b + (i << 11);
        bf16x8 A1[2][2], A2[2][2];
        #pragma unroll
        for (int t = 0; t < 2; ++t)
            #pragma unroll
            for (int s = 0; s < 2; ++s) {
                int off = (((t << 4) + c0) << 6) + (s << 5) + (q << 3);
                A1[t][s] = *(const bf16x8*)&Wp1[off];
                A2[t][s] = *(const bf16x8*)&Wp2[off];
            }
        #pragma unroll
        for (int cc = 0; cc < 2; ++cc) {
            int rb = (((w << 1) + cc) * 16 + c0) * PITCH;
            bf16x8 B0 = *(const bf16x8*)&Ha[rb + (q << 3)];
            bf16x8 B1 = *(const bf16x8*)&Ha[rb + 32 + (q << 3)];
            bf16x8 C0 = *(const bf16x8*)&Hb[rb + (q << 3)];
            bf16x8 C1 = *(const bf16x8*)&Hb[rb + 32 + (q << 3)];
            #pragma unroll
            for (int t = 0; t < 2; ++t) {
                f32x4 a1 = {0.f, 0.f, 0.f, 0.f};
                a1 = mfma16(A1[t][0], B0, a1);
                a1 = mfma16(A1[t][1], B1, a1);
                f32x4 a2 = {0.f, 0.f, 0.f, 0.f};
                a2 = mfma16(A2[t][0], C0, a2);
                a2 = mfma16(A2[t][1], C1, a2);
                union { uint2 u2; unsigned short s[4]; } p1, p2;
                #pragma unroll
                for (int r = 0; r < 4; ++r) {
                    p1.s[r] = f2bf(fmaxf(a1[r], 0.f));
                    p2.s[r] = f2bf(fmaxf(a2[r], 0.f));
                }
                *(uint2*)&R12[rb + (t << 4) + (q << 2)]      = p1.u2;
                *(uint2*)&R12[rb + 32 + (t << 4) + (q << 2)] = p2.u2;
            }
        }
    }
    __syncthreads();

    // ---------------- phase C: R12 -> h (W3a, K=64) + rank-1 + bias, relu, dot W3b, relu, store ----------------
    {
        const unsigned short* Wp3 = w3a + (i << 12);
        bf16x8 A3[4][2];
        #pragma unroll
        for (int t = 0; t < 4; ++t)
            #pragma unroll
            for (int s = 0; s < 2; ++s)
                A3[t][s] = *(const bf16x8*)&Wp3[(((t << 4) + c0) << 6) + (s << 5) + (q << 3)];

        f32x4 b3av[4], w3xv[4], w3bv[4];
        #pragma unroll
        for (int t = 0; t < 4; ++t) {
            int h0 = (i << 6) + (t << 4) + (q << 2);
            b3av[t] = *(const f32x4*)&b3a[h0];
            w3xv[t] = *(const f32x4*)&w3x[h0];
            w3bv[t] = *(const f32x4*)&W3b[h0];
        }
        const float bb = b3b[i];

        #pragma unroll
        for (int cc = 0; cc < 2; ++cc) {
            int ch = (w << 1) + cc;
            int rb = (ch * 16 + c0) * PITCH;
            float xd = xdiag[ch * 16 + c0];
            bf16x8 B0 = *(const bf16x8*)&R12[rb + (q << 3)];
            bf16x8 B1 = *(const bf16x8*)&R12[rb + 32 + (q << 3)];
            float p = 0.f;
            #pragma unroll
            for (int t = 0; t < 4; ++t) {
                f32x4 acc;
                #pragma unroll
                for (int r = 0; r < 4; ++r) acc[r] = b3av[t][r] + xd * w3xv[t][r];
                acc = mfma16(A3[t][0], B0, acc);
                acc = mfma16(A3[t][1], B1, acc);
                #pragma unroll
                for (int r = 0; r < 4; ++r) p += fmaxf(acc[r], 0.f) * w3bv[t][r];
            }
            p += __shfl_xor(p, 16);
            p += __shfl_xor(p, 32);
            if (lane < 16) {
                out[((b0 + ch * 16 + c0) << 6) + i] = fmaxf(p + bb, 0.f);
            }
        }
    }
}

extern "C" void kernel_launch(void* const* d_in, const int* in_sizes, int n_in,
                              void* d_out, int out_size, void* d_ws, size_t ws_size,
                              hipStream_t stream) {
    (void)in_sizes; (void)n_in; (void)out_size; (void)ws_size;
    const float* x   = (const float*)d_in[0];
    const float* W1a = (const float*)d_in[1];
    const float* W1b = (const float*)d_in[2];
    const float* W2a = (const float*)d_in[3];
    const float* W2b = (const float*)d_in[4];
    const float* W3a = (const float*)d_in[5];
    const float* b3a = (const float*)d_in[6];
    const float* W3b = (const float*)d_in[7];
    const float* b3b = (const float*)d_in[8];
    float* out = (float*)d_out;
    unsigned short* wsu = (unsigned short*)d_ws;
    float* w3x = (float*)(wsu + WS_END);

    prep_kernel<<<4096, 256, 0, stream>>>(x, W1a, W1b, W2a, W2b, W3a, wsu, w3x);
    main_kernel<<<(NBATCH / TB) * 64, 256, 0, stream>>>(x, b3a, W3b, b3b, wsu, w3x, out);
}

// Round 2
// 135.885 us; speedup vs baseline: 1.9563x; 1.9563x over previous
//
#include <hip/hip_runtime.h>

// N=64 nodes, H=64, M=32, B=16384.
// Grid: 512 blocks = 64 i-values x 8 batch-groups; 4 waves/block, no __syncthreads.
// Each wave: all weights for node i in registers (bf16 MFMA frags), loops over 32
// chunks of 16 batch rows. Phase transitions via per-wave-private LDS scratch.

typedef short bf16x8 __attribute__((ext_vector_type(8)));
typedef float f32x4  __attribute__((ext_vector_type(4)));
typedef unsigned int u32x4 __attribute__((ext_vector_type(4)));
typedef unsigned int u32x2 __attribute__((ext_vector_type(2)));

#define PITCH_S    72         // shorts per LDS row (144B -> only 2-way bank alias on b128)
#define WAVE_LDS_S 3456       // 3 buffers (Ha,Hb,R12) * 16 rows * 72

__device__ __forceinline__ unsigned int pack2(float a, float b) {
    // round-to-nearest (ties away) f32->bf16 pair pack: 2 adds + 1 v_perm_b32
    union { float f; unsigned int u; } ua, ub; ua.f = a; ub.f = b;
    return __builtin_amdgcn_perm(ub.u + 0x8000u, ua.u + 0x8000u, 0x07060302u);
}

__device__ __forceinline__ f32x4 mfma16(bf16x8 a, bf16x8 b, f32x4 c) {
    return __builtin_amdgcn_mfma_f32_16x16x32_bf16(a, b, c, 0, 0, 0);
}

__device__ __forceinline__ bf16x8 cvt_frag(const float* __restrict__ p) {
    f32x4 f0 = *(const f32x4*)p;
    f32x4 f1 = *(const f32x4*)(p + 4);
    union { u32x4 u; bf16x8 v; } r;
    r.u[0] = pack2(f0[0], f0[1]);
    r.u[1] = pack2(f0[2], f0[3]);
    r.u[2] = pack2(f1[0], f1[1]);
    r.u[3] = pack2(f1[2], f1[3]);
    return r.v;
}

__device__ __forceinline__ bf16x8 cvt_frag_m(const float* __restrict__ p, const unsigned int* M) {
    f32x4 f0 = *(const f32x4*)p;
    f32x4 f1 = *(const f32x4*)(p + 4);
    union { u32x4 u; bf16x8 v; } r;
    r.u[0] = pack2(f0[0], f0[1]) & M[0];
    r.u[1] = pack2(f0[2], f0[3]) & M[1];
    r.u[2] = pack2(f1[0], f1[1]) & M[2];
    r.u[3] = pack2(f1[2], f1[3]) & M[3];
    return r.v;
}

__global__ __launch_bounds__(256) void prep_x(const float* __restrict__ x,
                                              unsigned short* __restrict__ xb) {
    int j = (blockIdx.x * 256 + threadIdx.x) * 8;
    f32x4 a = *(const f32x4*)&x[j];
    f32x4 b = *(const f32x4*)&x[j + 4];
    u32x4 r = { pack2(a[0], a[1]), pack2(a[2], a[3]), pack2(b[0], b[1]), pack2(b[2], b[3]) };
    *(u32x4*)&xb[j] = r;
}

__global__ __launch_bounds__(256, 2) void main_kernel(
    const float* __restrict__ x,
    const float* __restrict__ W1a, const float* __restrict__ W1b,
    const float* __restrict__ W2a, const float* __restrict__ W2b,
    const float* __restrict__ W3a, const float* __restrict__ b3a,
    const float* __restrict__ W3b, const float* __restrict__ b3b,
    const unsigned short* __restrict__ xb,
    float* __restrict__ out)
{
    __shared__ unsigned short lds[4 * WAVE_LDS_S];

    const int i    = blockIdx.x & 63;   // same-i blocks land on same XCD (stride 64 % 8 == 0)
    const int bg   = blockIdx.x >> 6;   // 0..7
    const int tid  = threadIdx.x;
    const int w    = tid >> 6;
    const int lane = tid & 63;
    const int q    = lane >> 4;
    const int c0   = lane & 15;

    // masks to zero weight input-column i (equivalent to masking x column i)
    unsigned int M[2][4];
    {
        const unsigned int halfmask = (i & 1) ? 0x0000FFFFu : 0xFFFF0000u;
        const int dz = (i >> 1) & 3;
        #pragma unroll
        for (int s = 0; s < 2; ++s) {
            bool hit = ((i >> 3) == s * 4 + q);
            #pragma unroll
            for (int d = 0; d < 4; ++d)
                M[s][d] = (hit && d == dz) ? halfmask : 0xFFFFFFFFu;
        }
    }

    // ---- one-time: all weights for node i into registers as MFMA A-fragments ----
    bf16x8 A1[4][2], A2[4][2];
    {
        const float* p1 = W1a + (i << 12);
        const float* p2 = W2a + (i << 12);
        #pragma unroll
        for (int t = 0; t < 4; ++t)
            #pragma unroll
            for (int s = 0; s < 2; ++s) {
                int off = (((t << 4) + c0) << 6) + (s << 5) + (q << 3);
                A1[t][s] = cvt_frag_m(p1 + off, M[s]);
                A2[t][s] = cvt_frag_m(p2 + off, M[s]);
            }
    }
    bf16x8 F1[2][2], F2[2][2];
    {
        const float* p1 = W1b + (i << 11);
        const float* p2 = W2b + (i << 11);
        #pragma unroll
        for (int t = 0; t < 2; ++t)
            #pragma unroll
            for (int s = 0; s < 2; ++s) {
                int off = (((t << 4) + c0) << 6) + (s << 5) + (q << 3);
                F1[t][s] = cvt_frag(p1 + off);
                F2[t][s] = cvt_frag(p2 + off);
            }
    }
    bf16x8 A3[4][2];
    {
        const float* p3 = W3a + (i << 13);
        #pragma unroll
        for (int t = 0; t < 4; ++t)
            #pragma unroll
            for (int s = 0; s < 2; ++s)
                A3[t][s] = cvt_frag(p3 + (((t << 4) + c0) << 7) + (s << 5) + (q << 3));
    }
    f32x4 b3av[4], w3xv[4], w3bv[4];
    #pragma unroll
    for (int t = 0; t < 4; ++t) {
        int h0 = (i << 6) + (t << 4) + (q << 2);
        b3av[t] = *(const f32x4*)&b3a[h0];
        w3bv[t] = *(const f32x4*)&W3b[h0];
        #pragma unroll
        for (int r = 0; r < 4; ++r)
            w3xv[t][r] = W3a[(i << 13) + (((t << 4) + (q << 2) + r) << 7) + 64 + i];
    }
    const float bb = b3b[i];

    // per-wave LDS scratch (no cross-wave sharing -> no barriers)
    unsigned short* Hw       = &lds[w * WAVE_LDS_S + c0 * PITCH_S + (q << 2)]; // write base
    const unsigned short* Hr = &lds[w * WAVE_LDS_S + c0 * PITCH_S + (q << 3)]; // read base

    const int rbase0 = (((bg << 2) + w) << 9); // this wave's first batch row (512 rows total)

    // prefetch chunk 0
    int row = rbase0 + c0;
    bf16x8 XB0 = *(const bf16x8*)&xb[(row << 6) + (q << 3)];
    bf16x8 XB1 = *(const bf16x8*)&xb[(row << 6) + 32 + (q << 3)];
    float   xd = x[(row << 6) + i];

    for (int k = 0; k < 32; ++k) {
        // prefetch next chunk (clamped on last iter)
        int nrow = rbase0 + ((k < 31 ? k + 1 : 31) << 4) + c0;
        bf16x8 nXB0 = *(const bf16x8*)&xb[(nrow << 6) + (q << 3)];
        bf16x8 nXB1 = *(const bf16x8*)&xb[(nrow << 6) + 32 + (q << 3)];
        float   nxd = x[(nrow << 6) + i];

        // ---- phase A: x -> Ha (W1a), x -> Hb (W2a) ----
        #pragma unroll
        for (int t = 0; t < 4; ++t) {
            f32x4 a1 = {0.f, 0.f, 0.f, 0.f}, a2 = {0.f, 0.f, 0.f, 0.f};
            a1 = mfma16(A1[t][0], XB0, a1); a1 = mfma16(A1[t][1], XB1, a1);
            a2 = mfma16(A2[t][0], XB0, a2); a2 = mfma16(A2[t][1], XB1, a2);
            u32x2 w1 = { pack2(fmaxf(a1[0], 0.f), fmaxf(a1[1], 0.f)),
                         pack2(fmaxf(a1[2], 0.f), fmaxf(a1[3], 0.f)) };
            u32x2 w2 = { pack2(fmaxf(a2[0], 0.f), fmaxf(a2[1], 0.f)),
                         pack2(fmaxf(a2[2], 0.f), fmaxf(a2[3], 0.f)) };
            *(u32x2*)&Hw[t << 4]          = w1;
            *(u32x2*)&Hw[1152 + (t << 4)] = w2;
        }
        bf16x8 HB0 = *(const bf16x8*)&Hr[0];
        bf16x8 HB1 = *(const bf16x8*)&Hr[32];
        bf16x8 GB0 = *(const bf16x8*)&Hr[1152];
        bf16x8 GB1 = *(const bf16x8*)&Hr[1152 + 32];

        // ---- phase B: Ha -> r1, Hb -> r2 (into R12) ----
        #pragma unroll
        for (int t = 0; t < 2; ++t) {
            f32x4 a1 = {0.f, 0.f, 0.f, 0.f}, a2 = {0.f, 0.f, 0.f, 0.f};
            a1 = mfma16(F1[t][0], HB0, a1); a1 = mfma16(F1[t][1], HB1, a1);
            a2 = mfma16(F2[t][0], GB0, a2); a2 = mfma16(F2[t][1], GB1, a2);
            u32x2 w1 = { pack2(fmaxf(a1[0], 0.f), fmaxf(a1[1], 0.f)),
                         pack2(fmaxf(a1[2], 0.f), fmaxf(a1[3], 0.f)) };
            u32x2 w2 = { pack2(fmaxf(a2[0], 0.f), fmaxf(a2[1], 0.f)),
                         pack2(fmaxf(a2[2], 0.f), fmaxf(a2[3], 0.f)) };
            *(u32x2*)&Hw[2304 + (t << 4)]      = w1;
            *(u32x2*)&Hw[2304 + 32 + (t << 4)] = w2;
        }
        bf16x8 RB0 = *(const bf16x8*)&Hr[2304];
        bf16x8 RB1 = *(const bf16x8*)&Hr[2304 + 32];

        // ---- phase C: R12 -> h (W3a first 64 cols) + rank-1(x2) + bias; dot W3b ----
        float p = 0.f;
        #pragma unroll
        for (int t = 0; t < 4; ++t) {
            f32x4 acc;
            #pragma unroll
            for (int r = 0; r < 4; ++r) acc[r] = fmaf(xd, w3xv[t][r], b3av[t][r]);
            acc = mfma16(A3[t][0], RB0, acc);
            acc = mfma16(A3[t][1], RB1, acc);
            #pragma unroll
            for (int r = 0; r < 4; ++r) p = fmaf(fmaxf(acc[r], 0.f), w3bv[t][r], p);
        }
        p += __shfl_xor(p, 16);
        p += __shfl_xor(p, 32);
        if (lane < 16) out[(row << 6) + i] = fmaxf(p + bb, 0.f);

        row = nrow; XB0 = nXB0; XB1 = nXB1; xd = nxd;
    }
}

extern "C" void kernel_launch(void* const* d_in, const int* in_sizes, int n_in,
                              void* d_out, int out_size, void* d_ws, size_t ws_size,
                              hipStream_t stream) {
    (void)in_sizes; (void)n_in; (void)out_size; (void)ws_size;
    const float* x   = (const float*)d_in[0];
    const float* W1a = (const float*)d_in[1];
    const float* W1b = (const float*)d_in[2];
    const float* W2a = (const float*)d_in[3];
    const float* W2b = (const float*)d_in[4];
    const float* W3a = (const float*)d_in[5];
    const float* b3a = (const float*)d_in[6];
    const float* W3b = (const float*)d_in[7];
    const float* b3b = (const float*)d_in[8];
    float* out = (float*)d_out;
    unsigned short* xb = (unsigned short*)d_ws;

    prep_x<<<512, 256, 0, stream>>>(x, xb);                 // 16384*64 = 1M elems, x8/thread
    main_kernel<<<512, 256, 0, stream>>>(x, W1a, W1b, W2a, W2b, W3a, b3a, W3b, b3b, xb, out);
}

// Round 3
// 131.673 us; speedup vs baseline: 2.0189x; 1.0320x over previous
//
#include <hip/hip_runtime.h>

// N=64 nodes, H=64, M=32, B=16384.
// Grid: 512 blocks = 64 i-values x 8 batch-groups; 4 waves/block; NO __shared__.
// All weights for node i live in registers as bf16 MFMA A-fragments, with the
// K-columns of W1b/W2b/W3a permuted (sigma) so each phase's MFMA D registers,
// after relu+bf16 pack, ARE the next phase's B-operand fragments in-register.
// Batch stays in lane&15 through the whole chain; no LDS round-trips at all.

typedef short bf16x8 __attribute__((ext_vector_type(8)));
typedef float f32x4  __attribute__((ext_vector_type(4)));
typedef unsigned int u32x4 __attribute__((ext_vector_type(4)));

__device__ __forceinline__ unsigned int pack2(float a, float b) {
    // f32->bf16 pair pack, round-to-nearest-ties-away: 2 adds + 1 v_perm (a -> low16)
    union { float f; unsigned int u; } ua, ub; ua.f = a; ub.f = b;
    return __builtin_amdgcn_perm(ub.u + 0x8000u, ua.u + 0x8000u, 0x07060302u);
}

__device__ __forceinline__ f32x4 mfma16(bf16x8 a, bf16x8 b, f32x4 c) {
    return __builtin_amdgcn_mfma_f32_16x16x32_bf16(a, b, c, 0, 0, 0);
}

// pack two relu'd f32x4 D-blocks into one bf16x8 B-operand fragment
__device__ __forceinline__ bf16x8 pack_frag(f32x4 lo, f32x4 hi) {
    union { u32x4 u; bf16x8 v; } r;
    r.u[0] = pack2(fmaxf(lo[0], 0.f), fmaxf(lo[1], 0.f));
    r.u[1] = pack2(fmaxf(lo[2], 0.f), fmaxf(lo[3], 0.f));
    r.u[2] = pack2(fmaxf(hi[0], 0.f), fmaxf(hi[1], 0.f));
    r.u[3] = pack2(fmaxf(hi[2], 0.f), fmaxf(hi[3], 0.f));
    return r.v;
}

// convert 2x f32x4 (possibly non-adjacent) into a bf16x8 A-fragment
__device__ __forceinline__ bf16x8 cvt_frag2(const float* __restrict__ plo,
                                            const float* __restrict__ phi) {
    f32x4 f0 = *(const f32x4*)plo;
    f32x4 f1 = *(const f32x4*)phi;
    union { u32x4 u; bf16x8 v; } r;
    r.u[0] = pack2(f0[0], f0[1]);
    r.u[1] = pack2(f0[2], f0[3]);
    r.u[2] = pack2(f1[0], f1[1]);
    r.u[3] = pack2(f1[2], f1[3]);
    return r.v;
}

__device__ __forceinline__ bf16x8 cvt_frag2_m(const float* __restrict__ plo,
                                              const float* __restrict__ phi,
                                              const unsigned int* M) {
    f32x4 f0 = *(const f32x4*)plo;
    f32x4 f1 = *(const f32x4*)phi;
    union { u32x4 u; bf16x8 v; } r;
    r.u[0] = pack2(f0[0], f0[1]) & M[0];
    r.u[1] = pack2(f0[2], f0[3]) & M[1];
    r.u[2] = pack2(f1[0], f1[1]) & M[2];
    r.u[3] = pack2(f1[2], f1[3]) & M[3];
    return r.v;
}

__global__ __launch_bounds__(256) void prep_x(const float* __restrict__ x,
                                              unsigned short* __restrict__ xb) {
    int j = (blockIdx.x * 256 + threadIdx.x) * 8;
    f32x4 a = *(const f32x4*)&x[j];
    f32x4 b = *(const f32x4*)&x[j + 4];
    u32x4 r = { pack2(a[0], a[1]), pack2(a[2], a[3]), pack2(b[0], b[1]), pack2(b[2], b[3]) };
    *(u32x4*)&xb[j] = r;
}

__global__ __launch_bounds__(256, 2) void main_kernel(
    const float* __restrict__ x,
    const float* __restrict__ W1a, const float* __restrict__ W1b,
    const float* __restrict__ W2a, const float* __restrict__ W2b,
    const float* __restrict__ W3a, const float* __restrict__ b3a,
    const float* __restrict__ W3b, const float* __restrict__ b3b,
    const unsigned short* __restrict__ xb,
    float* __restrict__ out)
{
    const int i    = blockIdx.x & 63;   // same-i blocks -> same XCD (stride 64 % 8 == 0)
    const int bg   = blockIdx.x >> 6;   // 0..7
    const int tid  = threadIdx.x;
    const int w    = tid >> 6;
    const int lane = tid & 63;
    const int q    = lane >> 4;
    const int c0   = lane & 15;

    // masks zeroing weight input-column i of W1a/W2a (== masking x column i)
    unsigned int M[2][4];
    {
        const unsigned int halfmask = (i & 1) ? 0x0000FFFFu : 0xFFFF0000u;
        const int dz = (i >> 1) & 3;
        #pragma unroll
        for (int s = 0; s < 2; ++s) {
            bool hit = ((i >> 3) == s * 4 + q);
            #pragma unroll
            for (int d = 0; d < 4; ++d)
                M[s][d] = (hit && d == dz) ? halfmask : 0xFFFFFFFFu;
        }
    }

    // ---- weights for node i -> registers (bf16 A-fragments), K-permuted where needed ----
    // Phase A (W1a/W2a): natural K order. frag elem j = W[i][t*16+c0][s*32+q*8+j]
    bf16x8 A1[4][2], A2[4][2];
    {
        const float* p1 = W1a + (i << 12);
        const float* p2 = W2a + (i << 12);
        #pragma unroll
        for (int t = 0; t < 4; ++t)
            #pragma unroll
            for (int s = 0; s < 2; ++s) {
                int off = (((t << 4) + c0) << 6) + (s << 5) + (q << 3);
                A1[t][s] = cvt_frag2_m(p1 + off, p1 + off + 4, M[s]);
                A2[t][s] = cvt_frag2_m(p2 + off, p2 + off + 4, M[s]);
            }
    }
    // Phase B (W1b/W2b): K permuted by sigma(s,q,j) = 32s + 16*(j>>2) + 4q + (j&3)
    bf16x8 F1[2][2], F2[2][2];
    {
        const float* p1 = W1b + (i << 11);
        const float* p2 = W2b + (i << 11);
        #pragma unroll
        for (int t = 0; t < 2; ++t)
            #pragma unroll
            for (int s = 0; s < 2; ++s) {
                int base = (((t << 4) + c0) << 6) + (s << 5) + (q << 2);
                F1[t][s] = cvt_frag2(p1 + base, p1 + base + 16);
                F2[t][s] = cvt_frag2(p2 + base, p2 + base + 16);
            }
    }
    // Phase C (W3a, first 64 concat cols): col = 32s + 16*(j>>2) + 4q + (j&3)
    bf16x8 A3[4][2];
    {
        const float* p3 = W3a + (i << 13);
        #pragma unroll
        for (int t = 0; t < 4; ++t)
            #pragma unroll
            for (int s = 0; s < 2; ++s) {
                int base = (((t << 4) + c0) << 7) + (s << 5) + (q << 2);
                A3[t][s] = cvt_frag2(p3 + base, p3 + base + 16);
            }
    }
    f32x4 b3av[4], w3xv[4], w3bv[4];
    #pragma unroll
    for (int t = 0; t < 4; ++t) {
        int h0 = (i << 6) + (t << 4) + (q << 2);
        b3av[t] = *(const f32x4*)&b3a[h0];
        w3bv[t] = *(const f32x4*)&W3b[h0];
        #pragma unroll
        for (int r = 0; r < 4; ++r)
            w3xv[t][r] = W3a[(i << 13) + (((t << 4) + (q << 2) + r) << 7) + 64 + i];
    }
    const float bb = b3b[i];

    const int rbase0 = (((bg << 2) + w) << 9); // this wave's first batch row (512 rows)

    // prefetch chunk 0
    int row = rbase0 + c0;
    bf16x8 XB0 = *(const bf16x8*)&xb[(row << 6) + (q << 3)];
    bf16x8 XB1 = *(const bf16x8*)&xb[(row << 6) + 32 + (q << 3)];
    float   xd = x[(row << 6) + i];

    for (int k = 0; k < 32; ++k) {
        int nrow = rbase0 + ((k < 31 ? k + 1 : 31) << 4) + c0;
        bf16x8 nXB0 = *(const bf16x8*)&xb[(nrow << 6) + (q << 3)];
        bf16x8 nXB1 = *(const bf16x8*)&xb[(nrow << 6) + 32 + (q << 3)];
        float   nxd = x[(nrow << 6) + i];

        // ---- phase A: x -> Ha (W1a), x -> Hb (W2a); D regs -> B-frags in-register ----
        f32x4 a1[4], a2[4];
        #pragma unroll
        for (int t = 0; t < 4; ++t) {
            f32x4 z = {0.f, 0.f, 0.f, 0.f};
            f32x4 u = mfma16(A1[t][0], XB0, z);
            a1[t]   = mfma16(A1[t][1], XB1, u);
            f32x4 v = mfma16(A2[t][0], XB0, z);
            a2[t]   = mfma16(A2[t][1], XB1, v);
        }
        bf16x8 HB0 = pack_frag(a1[0], a1[1]);
        bf16x8 HB1 = pack_frag(a1[2], a1[3]);
        bf16x8 GB0 = pack_frag(a2[0], a2[1]);
        bf16x8 GB1 = pack_frag(a2[2], a2[3]);

        // ---- phase B: Ha -> r1 (W1b), Hb -> r2 (W2b) ----
        f32x4 b1[2], b2[2];
        #pragma unroll
        for (int t = 0; t < 2; ++t) {
            f32x4 z = {0.f, 0.f, 0.f, 0.f};
            f32x4 u = mfma16(F1[t][0], HB0, z);
            b1[t]   = mfma16(F1[t][1], HB1, u);
            f32x4 v = mfma16(F2[t][0], GB0, z);
            b2[t]   = mfma16(F2[t][1], GB1, v);
        }
        bf16x8 RB0 = pack_frag(b1[0], b1[1]);   // r1 -> A3 s=0 slots
        bf16x8 RB1 = pack_frag(b2[0], b2[1]);   // r2 -> A3 s=1 slots

        // ---- phase C: h = W3a'*[r1;r2] + xd*w3x + b3a; out = relu(dot(relu(h), w3b) + bb) ----
        float p = 0.f;
        #pragma unroll
        for (int t = 0; t < 4; ++t) {
            f32x4 acc;
            #pragma unroll
            for (int r = 0; r < 4; ++r) acc[r] = fmaf(xd, w3xv[t][r], b3av[t][r]);
            acc = mfma16(A3[t][0], RB0, acc);
            acc = mfma16(A3[t][1], RB1, acc);
            #pragma unroll
            for (int r = 0; r < 4; ++r) p = fmaf(fmaxf(acc[r], 0.f), w3bv[t][r], p);
        }
        p += __shfl_xor(p, 16);
        p += __shfl_xor(p, 32);
        if (lane < 16) out[(row << 6) + i] = fmaxf(p + bb, 0.f);

        row = nrow; XB0 = nXB0; XB1 = nXB1; xd = nxd;
    }
}

extern "C" void kernel_launch(void* const* d_in, const int* in_sizes, int n_in,
                              void* d_out, int out_size, void* d_ws, size_t ws_size,
                              hipStream_t stream) {
    (void)in_sizes; (void)n_in; (void)out_size; (void)ws_size;
    const float* x   = (const float*)d_in[0];
    const float* W1a = (const float*)d_in[1];
    const float* W1b = (const float*)d_in[2];
    const float* W2a = (const float*)d_in[3];
    const float* W2b = (const float*)d_in[4];
    const float* W3a = (const float*)d_in[5];
    const float* b3a = (const float*)d_in[6];
    const float* W3b = (const float*)d_in[7];
    const float* b3b = (const float*)d_in[8];
    float* out = (float*)d_out;
    unsigned short* xb = (unsigned short*)d_ws;

    prep_x<<<512, 256, 0, stream>>>(x, xb);
    main_kernel<<<512, 256, 0, stream>>>(x, W1a, W1b, W2a, W2b, W3a, b3a, W3b, b3b, xb, out);
}